// Round 3
// baseline (380.748 us; speedup 1.0000x reference)
//
#include <hip/hip_runtime.h>
#include <math.h>

#define NCAP 10
#define IC   6912
#define STOT (64 * NCAP * 16)        // 10240 floats per s image
#define JPB  16
#define NBLK (IC / JPB)              // 432 sweep blocks
#define R1B  16                      // stage2 slots
#define R1K  (NBLK / R1B)            // 27 partials summed per reduce1 block

typedef __attribute__((ext_vector_type(4))) float f32x4;
typedef __attribute__((ext_vector_type(8))) short bf16x8;

// fp32 -> bf16 RNE
static __device__ inline unsigned short f2bf(float f) {
    unsigned int u = __float_as_uint(f);
    unsigned int r = u + 0x7FFFu + ((u >> 16) & 1u);
    return (unsigned short)(r >> 16);
}

// Barrier-free MFMA routing sweep.
// Block: 512 threads = 8 waves = 4 b-groups x 2 j-waves. No LDS staging:
// MFMA operands loaded straight from global (W: 8 scattered dwords/lane with
// o=lane&15 covering full 64B lines; x: 2 float4). Lanes with kq>=2 carry the
// K=16..31 zero padding as zero fragments -- no pad memory, no barriers in the
// j loop. Layouts (m89-verified, round-2-passed): A[m=lane&15][k=kq*8+t],
// B[k=kq*8+t][col=lane&15], D col=lane&15(=b) row=kq*4+reg(=o).
__global__ __launch_bounds__(512) void sweep_kernel(
    const float* __restrict__ x, const float* __restrict__ W,
    const float* __restrict__ vsum, float* __restrict__ s_part, int iter)
{
    // combine buffer: slot = (b*10+n)*16 + kq*4 + b*4 (pad -> lane stride 164
    // dwords == 4 mod 32 -> conflict-free)
    __shared__ float cbuf[STOT + 64 * 4];

    const int tid  = threadIdx.x;
    const int lane = tid & 63;
    const int wave = tid >> 6;      // 0..7
    const int bg   = wave & 3;      // b-group
    const int jw   = wave >> 2;     // 0..1
    const int bl   = lane & 15;
    const int kq   = lane >> 4;     // 0..3
    const int b    = bg * 16 + bl;
    const bool act = (kq < 2);      // lanes holding real K (k<16)
    const int j0   = blockIdx.x * JPB + jw * 8;

    f32x4 vv[NCAP];
    if (iter > 0) {
        #pragma unroll
        for (int n = 0; n < NCAP; ++n)
            vv[n] = *(const f32x4*)&vsum[(b * NCAP + n) * 16 + kq * 4];
    }

    f32x4 sac[NCAP];
    #pragma unroll
    for (int n = 0; n < NCAP; ++n) sac[n] = (f32x4){0.f, 0.f, 0.f, 0.f};

    for (int jt = 0; jt < 8; ++jt) {
        const int j = j0 + jt;

        // B fragment: x[b, j, k] (zero for kq>=2)
        bf16x8 xb = (bf16x8){0, 0, 0, 0, 0, 0, 0, 0};
        if (act) {
            const float4* xp = (const float4*)(x + ((size_t)b * IC + j) * 16);
            float4 x0 = xp[kq * 2 + 0];
            float4 x1 = xp[kq * 2 + 1];
            xb[0] = (short)f2bf(x0.x); xb[1] = (short)f2bf(x0.y);
            xb[2] = (short)f2bf(x0.z); xb[3] = (short)f2bf(x0.w);
            xb[4] = (short)f2bf(x1.x); xb[5] = (short)f2bf(x1.y);
            xb[6] = (short)f2bf(x1.z); xb[7] = (short)f2bf(x1.w);
        }

        // u[n] = W[n,j]^T (M=o) x x (N=b), K=i
        f32x4 u[NCAP];
        #pragma unroll
        for (int n = 0; n < NCAP; ++n) {
            bf16x8 af = (bf16x8){0, 0, 0, 0, 0, 0, 0, 0};
            if (act) {
                // W[n][j][i=kq*8+t][o=bl]; element t at stride 16 dwords
                const float* wp = W + ((size_t)n * IC + j) * 256 + kq * 128 + bl;
                float w0 = wp[0];   float w1 = wp[16];  float w2 = wp[32];  float w3 = wp[48];
                float w4 = wp[64];  float w5 = wp[80];  float w6 = wp[96];  float w7 = wp[112];
                af[0] = (short)f2bf(w0); af[1] = (short)f2bf(w1);
                af[2] = (short)f2bf(w2); af[3] = (short)f2bf(w3);
                af[4] = (short)f2bf(w4); af[5] = (short)f2bf(w5);
                af[6] = (short)f2bf(w6); af[7] = (short)f2bf(w7);
            }
            u[n] = __builtin_amdgcn_mfma_f32_16x16x32_bf16(
                af, xb, (f32x4){0.f, 0.f, 0.f, 0.f}, 0, 0, 0);
        }

        if (iter == 0) {
            #pragma unroll
            for (int n = 0; n < NCAP; ++n) {
                sac[n][0] = fmaf(0.1f, u[n][0], sac[n][0]);
                sac[n][1] = fmaf(0.1f, u[n][1], sac[n][1]);
                sac[n][2] = fmaf(0.1f, u[n][2], sac[n][2]);
                sac[n][3] = fmaf(0.1f, u[n][3], sac[n][3]);
            }
        } else {
            // bb[n] = sum_o u*vsum: 4 in-lane + butterfly over lane bits 4,5 (kq)
            float bb_[NCAP];
            #pragma unroll
            for (int n = 0; n < NCAP; ++n) {
                float p = u[n][0] * vv[n][0] + u[n][1] * vv[n][1]
                        + u[n][2] * vv[n][2] + u[n][3] * vv[n][3];
                p += __shfl_xor(p, 16);
                p += __shfl_xor(p, 32);
                bb_[n] = p;
            }
            float m = bb_[0];
            #pragma unroll
            for (int n = 1; n < NCAP; ++n) m = fmaxf(m, bb_[n]);
            float ssum = 0.f;
            float c[NCAP];
            #pragma unroll
            for (int n = 0; n < NCAP; ++n) { c[n] = __expf(bb_[n] - m); ssum += c[n]; }
            const float inv = 1.0f / ssum;
            #pragma unroll
            for (int n = 0; n < NCAP; ++n) {
                const float cn = c[n] * inv;
                sac[n][0] = fmaf(cn, u[n][0], sac[n][0]);
                sac[n][1] = fmaf(cn, u[n][1], sac[n][1]);
                sac[n][2] = fmaf(cn, u[n][2], sac[n][2]);
                sac[n][3] = fmaf(cn, u[n][3], sac[n][3]);
            }
        }
    }

    // combine jw=1 into jw=0 through LDS (one barrier per block, at the end)
    const int sbase = (b * NCAP) * 16 + kq * 4 + b * 4;
    if (jw == 1) {
        #pragma unroll
        for (int n = 0; n < NCAP; ++n)
            *(f32x4*)&cbuf[sbase + n * 16] = sac[n];
    }
    __syncthreads();
    if (jw == 0) {
        float* sp = s_part + (size_t)blockIdx.x * STOT;
        #pragma unroll
        for (int n = 0; n < NCAP; ++n) {
            f32x4 t = *(const f32x4*)&cbuf[sbase + n * 16];
            t[0] += sac[n][0]; t[1] += sac[n][1];
            t[2] += sac[n][2]; t[3] += sac[n][3];
            *(f32x4*)&sp[(b * NCAP + n) * 16 + kq * 4] = t;
        }
    }
}

// stage 1: sum 432 partials down to 16; grid (10, 16) = 160 blocks
__global__ __launch_bounds__(256) void reduce1_kernel(
    const float* __restrict__ s_part, float* __restrict__ stage2)
{
    const int g4 = blockIdx.x * 256 + threadIdx.x;   // float4 index 0..2559
    const int k0 = blockIdx.y * R1K;
    const float4* sp4 = (const float4*)s_part;
    float4 acc = make_float4(0.f, 0.f, 0.f, 0.f);
    #pragma unroll 9
    for (int k = 0; k < R1K; ++k) {
        float4 v = sp4[(size_t)(k0 + k) * (STOT / 4) + g4];
        acc.x += v.x; acc.y += v.y; acc.z += v.z; acc.w += v.w;
    }
    ((float4*)stage2)[(size_t)blockIdx.y * (STOT / 4) + g4] = acc;
}

// stage 2: sum 16, squash, maintain vsum / write out; grid 40 x 256
__global__ __launch_bounds__(256) void reduce2_kernel(
    const float* __restrict__ stage2, float* __restrict__ vsum,
    float* __restrict__ out, int iter)
{
    const int g = blockIdx.x * 256 + threadIdx.x;   // 0..10239
    float acc = 0.f;
    #pragma unroll
    for (int kb = 0; kb < R1B; ++kb) acc += stage2[kb * STOT + g];

    float sq = acc * acc;          // squash over the 16 o's (o = lane bits 0..3)
    sq += __shfl_xor(sq, 1);
    sq += __shfl_xor(sq, 2);
    sq += __shfl_xor(sq, 4);
    sq += __shfl_xor(sq, 8);
    float scale = (sq / (1.f + sq)) / sqrtf(sq + 1e-7f);
    float v = scale * acc;

    if (iter == 2)      out[g] = v;
    else if (iter == 0) vsum[g] = v;
    else                vsum[g] += v;
}

extern "C" void kernel_launch(void* const* d_in, const int* in_sizes, int n_in,
                              void* d_out, int out_size, void* d_ws, size_t ws_size,
                              hipStream_t stream) {
    (void)in_sizes; (void)n_in; (void)out_size; (void)ws_size;
    const float* x = (const float*)d_in[0];   // [64, 6912, 16]
    const float* W = (const float*)d_in[1];   // [10, 6912, 16, 16]
    float* out = (float*)d_out;               // [64, 10, 16]

    float* s_part = (float*)d_ws;                             // 432 * 10240
    float* stage2 = s_part + (size_t)NBLK * STOT;             // 16 * 10240
    float* vsum   = stage2 + (size_t)R1B * STOT;              // 10240

    for (int iter = 0; iter < 3; ++iter) {
        sweep_kernel<<<NBLK, 512, 0, stream>>>(x, W, vsum, s_part, iter);
        reduce1_kernel<<<dim3(10, R1B), 256, 0, stream>>>(s_part, stage2);
        reduce2_kernel<<<40, 256, 0, stream>>>(stage2, vsum, out, iter);
    }
}

// Round 5
// 286.130 us; speedup vs baseline: 1.3307x; 1.3307x over previous
//
#include <hip/hip_runtime.h>
#include <math.h>

#define NCAP 10
#define IC   6912
#define NJG  384                  // j-groups (18 j each)
#define NSLOT (NJG * 2)           // 768 sweep blocks / part slots
#define WPAIRS ((IC * NCAP) / 2)  // 34560 W tile-pairs

typedef __attribute__((ext_vector_type(4))) float f32x4;
typedef __attribute__((ext_vector_type(8))) short bf16x8;

// fp32 -> bf16 RNE
static __device__ inline unsigned short f2bf(float f) {
    unsigned int u = __float_as_uint(f);
    unsigned int r = u + 0x7FFFu + ((u >> 16) & 1u);
    return (unsigned short)(r >> 16);
}

// Pre-transpose W (fp32 [n][j][i][o]) into bf16 MFMA A-fragment order:
// w_t[(j*10+n)*256 + l2*8 + t] where l2 = kq*16 + o (lane), k = i = kq*8+t.
// Pure streaming, NO block barriers: each wave transposes 16x16 tiles through
// its PRIVATE LDS region (wave64 lockstep; compiler orders ds ops via lgkmcnt).
// Double-buffered by iteration parity to kill LDS WAR serialization.
__global__ __launch_bounds__(256) void transpose_kernel(
    const float* __restrict__ W, unsigned short* __restrict__ w_t)
{
    __shared__ float lds[4 * 1312];          // 4 waves x 2 buffers x 2 regions x 328
    const int tid  = threadIdx.x;
    const int lane = tid & 63;
    const int wv   = tid >> 6;
    float* L0 = lds + wv * 1312;
    const int nw = gridDim.x * 4;
    const int gw = blockIdx.x * 4 + wv;
    const int lr  = lane & 31;
    const int reg = lane >> 5;               // which tile of the pair
    const int ia  = lr >> 2, oq = lr & 3;    // phase-1 roles
    const int o   = lr & 15, kq2 = lr >> 4;  // phase-2 roles

    const float4* W4 = (const float4*)W;
    int itc = 0;
    for (int p = gw; p < WPAIRS; p += nw, ++itc) {
        float* L = L0 + (itc & 1) * 656;
        const int tl = p * 2 + reg;          // tile id = j*10 + n
        const int n = tl % 10, j = tl / 10;
        const float4* src = W4 + ((size_t)n * IC + j) * 64;
        float4 a = src[lr];                  // i=ia,   o=oq*4..+3
        float4 c = src[lr + 32];             // i=ia+8, o=oq*4..+3
        *(float4*)&L[reg * 328 + ia * 20 + oq * 4] = a;
        *(float4*)&L[reg * 328 + (ia + 8) * 20 + oq * 4] = c;
        // phase 2: lane lr (=kq2*16+o) gathers A[m=o][k=kq2*8+t]
        bf16x8 fr;
        #pragma unroll
        for (int t = 0; t < 8; ++t)
            fr[t] = (short)f2bf(L[reg * 328 + (kq2 * 8 + t) * 20 + o]);
        *(bf16x8*)&w_t[(size_t)tl * 256 + lr * 8] = fr;  // 1 KB contiguous / wave
    }
}

// Barrier-free routing sweep. Block 256 = 4 waves = bg_l(2) x jw(2);
// block covers 32 b's (bh half), 18 j's (jw splits 9+9). Per j per wave:
// 2 float4 x loads + 10 bf16x8 w_t fragment loads (coalesced 512 B each),
// 10 MFMA, in-register softmax. No __syncthreads until the final combine.
// Layouts (R2-correctness-proven): A[m=o=lane&15][k=(lane>>4)*8+t],
// B[k][n=b=lane&15], D col=lane&15(=b) row=(lane>>4)*4+reg(=o); K 16->32
// zero-padded via zero fragments on lanes>=32.
__global__ __launch_bounds__(256, 3) void sweep_kernel(
    const float* __restrict__ x, const unsigned short* __restrict__ w_t,
    const float* __restrict__ vsum, float* __restrict__ part, int iter)
{
    __shared__ float cbuf[32 * 164];         // padded jw-combine buffer

    const int tid  = threadIdx.x;
    const int lane = tid & 63;
    const int wave = tid >> 6;
    const int bl   = lane & 15;
    const int kq   = lane >> 4;
    const bool act = (kq < 2);               // act lanes: lane == kq*16+bl < 32
    const int bh   = blockIdx.x & 1;
    const int jg   = blockIdx.x >> 1;
    const int bg_l = wave & 1;
    const int jw   = wave >> 1;
    const int b    = bh * 32 + bg_l * 16 + bl;
    const int j0   = jg * 18 + jw * 9;

    const f32x4 zf = (f32x4){0.f, 0.f, 0.f, 0.f};
    const bf16x8 zb = (bf16x8){0, 0, 0, 0, 0, 0, 0, 0};

    f32x4 vv[NCAP];
    if (iter > 0) {
        #pragma unroll
        for (int n = 0; n < NCAP; ++n)
            vv[n] = *(const f32x4*)&vsum[(b * NCAP + n) * 16 + kq * 4];
    }

    f32x4 sac[NCAP];
    #pragma unroll
    for (int n = 0; n < NCAP; ++n) sac[n] = zf;

    for (int jt = 0; jt < 9; ++jt) {
        const int j = j0 + jt;

        bf16x8 xb = zb;
        if (act) {
            const float* xp = x + ((size_t)b * IC + j) * 16 + kq * 8;
            float4 x0 = *(const float4*)xp;
            float4 x1 = *(const float4*)(xp + 4);
            xb[0] = (short)f2bf(x0.x); xb[1] = (short)f2bf(x0.y);
            xb[2] = (short)f2bf(x0.z); xb[3] = (short)f2bf(x0.w);
            xb[4] = (short)f2bf(x1.x); xb[5] = (short)f2bf(x1.y);
            xb[6] = (short)f2bf(x1.z); xb[7] = (short)f2bf(x1.w);
        }

        f32x4 u[NCAP];
        #pragma unroll
        for (int n = 0; n < NCAP; ++n) {
            bf16x8 af = zb;
            if (act)
                af = *(const bf16x8*)&w_t[((size_t)j * NCAP + n) * 256 + lane * 8];
            u[n] = __builtin_amdgcn_mfma_f32_16x16x32_bf16(af, xb, zf, 0, 0, 0);
        }

        if (iter == 0) {
            #pragma unroll
            for (int n = 0; n < NCAP; ++n) {
                sac[n][0] = fmaf(0.1f, u[n][0], sac[n][0]);
                sac[n][1] = fmaf(0.1f, u[n][1], sac[n][1]);
                sac[n][2] = fmaf(0.1f, u[n][2], sac[n][2]);
                sac[n][3] = fmaf(0.1f, u[n][3], sac[n][3]);
            }
        } else {
            float bb_[NCAP];
            #pragma unroll
            for (int n = 0; n < NCAP; ++n) {
                float p = u[n][0] * vv[n][0] + u[n][1] * vv[n][1]
                        + u[n][2] * vv[n][2] + u[n][3] * vv[n][3];
                p += __shfl_xor(p, 16);      // sum the 4 row-quads (o)
                p += __shfl_xor(p, 32);
                bb_[n] = p;
            }
            // softmax over n (no max-sub: |bb| bounded ~10s, fp32 exp safe)
            float ssum = 0.f;
            float c[NCAP];
            #pragma unroll
            for (int n = 0; n < NCAP; ++n) { c[n] = __expf(bb_[n]); ssum += c[n]; }
            const float inv = 1.0f / ssum;
            #pragma unroll
            for (int n = 0; n < NCAP; ++n) {
                const float cn = c[n] * inv;
                sac[n][0] = fmaf(cn, u[n][0], sac[n][0]);
                sac[n][1] = fmaf(cn, u[n][1], sac[n][1]);
                sac[n][2] = fmaf(cn, u[n][2], sac[n][2]);
                sac[n][3] = fmaf(cn, u[n][3], sac[n][3]);
            }
        }
    }

    // combine jw=1 into jw=0 (one barrier per block, at the very end)
    const int sb = (bg_l * 16 + bl) * 164 + kq * 4;
    if (jw == 1) {
        #pragma unroll
        for (int n = 0; n < NCAP; ++n)
            *(f32x4*)&cbuf[sb + n * 16] = sac[n];
    }
    __syncthreads();
    if (jw == 0) {
        float* pp = part + (size_t)blockIdx.x * 5120;
        #pragma unroll
        for (int n = 0; n < NCAP; ++n) {
            f32x4 t = *(const f32x4*)&cbuf[sb + n * 16];
            t[0] += sac[n][0]; t[1] += sac[n][1];
            t[2] += sac[n][2]; t[3] += sac[n][3];
            *(f32x4*)&pp[(bg_l * 16 + bl) * 160 + n * 16 + kq * 4] = t;
        }
    }
}

// Fused reduce (768 slots -> s) + squash + vsum/out. Grid 160 x 256.
// slot = jg*2 + bh holds the bh-half: element g lives at
// part[(jg*2+bh)*5120 + (g - bh*5120)] summed over jg.
__global__ __launch_bounds__(256) void reduce_kernel(
    const float* __restrict__ part, float* __restrict__ vsum,
    float* __restrict__ out, int iter)
{
    __shared__ float lds[3 * 64];
    const int tid = threadIdx.x;
    const int gi = tid & 63, rq = tid >> 6;
    const int g  = blockIdx.x * 64 + gi;         // 0..10239 (64 | 5120 boundary)
    const int bh = (g >= 5120) ? 1 : 0;
    const float* p0 = part + bh * 5120 + (g - bh * 5120);
    float acc = 0.f;
    for (int k = rq * 96; k < rq * 96 + 96; ++k)
        acc += p0[(size_t)k * 10240];             // 256 B coalesced per row
    if (rq > 0) lds[(rq - 1) * 64 + gi] = acc;
    __syncthreads();
    if (rq == 0) {
        acc += lds[gi] + lds[64 + gi] + lds[128 + gi];
        float sq = acc * acc;                     // squash over o = lane bits 0..3
        sq += __shfl_xor(sq, 1);
        sq += __shfl_xor(sq, 2);
        sq += __shfl_xor(sq, 4);
        sq += __shfl_xor(sq, 8);
        float scale = (sq / (1.f + sq)) / sqrtf(sq + 1e-7f);
        float v = scale * acc;
        if (iter == 2)      out[g] = v;
        else if (iter == 0) vsum[g] = v;
        else                vsum[g] += v;
    }
}

extern "C" void kernel_launch(void* const* d_in, const int* in_sizes, int n_in,
                              void* d_out, int out_size, void* d_ws, size_t ws_size,
                              hipStream_t stream) {
    (void)in_sizes; (void)n_in; (void)out_size; (void)ws_size;
    const float* x = (const float*)d_in[0];   // [64, 6912, 16]
    const float* W = (const float*)d_in[1];   // [10, 6912, 16, 16]
    float* out = (float*)d_out;               // [64, 10, 16]

    // ws carve-up (~51.2 MB)
    unsigned short* w_t = (unsigned short*)d_ws;              // 6912*10*256 bf16 = 35.4 MB
    float* part = (float*)(w_t + (size_t)IC * NCAP * 256);    // 768*5120*4 = 15.7 MB
    float* vsum = part + (size_t)NSLOT * 5120;                // 40 KB

    transpose_kernel<<<1024, 256, 0, stream>>>(W, w_t);
    for (int iter = 0; iter < 3; ++iter) {
        sweep_kernel<<<NSLOT, 256, 0, stream>>>(x, w_t, vsum, part, iter);
        reduce_kernel<<<160, 256, 0, stream>>>(part, vsum, out, iter);
    }
}

// Round 6
// 280.878 us; speedup vs baseline: 1.3556x; 1.0187x over previous
//
#include <hip/hip_runtime.h>
#include <math.h>

#define NCAP 10
#define IC   6912
#define NJG  384                  // j-groups (18 j each)
#define NSLOT (NJG * 2)           // part slots
#define WPAIRS ((IC * NCAP) / 2)  // 34560 W tile-pairs

typedef __attribute__((ext_vector_type(4))) float f32x4;
typedef __attribute__((ext_vector_type(8))) short bf16x8;

// fp32 -> bf16 RNE
static __device__ inline unsigned short f2bf(float f) {
    unsigned int u = __float_as_uint(f);
    unsigned int r = u + 0x7FFFu + ((u >> 16) & 1u);
    return (unsigned short)(r >> 16);
}

// Prep: blocks <1024 transpose W into MFMA A-fragment order (R5-proven body);
// blocks >=1024 (one per j) convert x into B-fragment order bf16.
__global__ __launch_bounds__(256) void prep_kernel(
    const float* __restrict__ x, const float* __restrict__ W,
    unsigned short* __restrict__ w_t, unsigned short* __restrict__ x_t,
    int use_xt)
{
    __shared__ float lds[4 * 1312];
    const int tid  = threadIdx.x;
    const int lane = tid & 63;
    const int wv   = tid >> 6;

    if (blockIdx.x < 1024) {
        float* L0 = lds + wv * 1312;
        const int gw = blockIdx.x * 4 + wv;
        const int lr  = lane & 31;
        const int reg = lane >> 5;
        const int ia  = lr >> 2, oq = lr & 3;
        const int o   = lr & 15, kq2 = lr >> 4;
        const float4* W4 = (const float4*)W;
        int itc = 0;
        for (int p = gw; p < WPAIRS; p += 4096, ++itc) {
            float* L = L0 + (itc & 1) * 656;
            const int tl = p * 2 + reg;          // tile id = j*10 + n
            const int n = tl % 10, j = tl / 10;
            const float4* src = W4 + ((size_t)n * IC + j) * 64;
            float4 a = src[lr];
            float4 c = src[lr + 32];
            *(float4*)&L[reg * 328 + ia * 20 + oq * 4] = a;
            *(float4*)&L[reg * 328 + (ia + 8) * 20 + oq * 4] = c;
            bf16x8 fr;
            #pragma unroll
            for (int t = 0; t < 8; ++t)
                fr[t] = (short)f2bf(L[reg * 328 + (kq2 * 8 + t) * 20 + o]);
            *(bf16x8*)&w_t[(size_t)tl * 256 + lr * 8] = fr;
        }
    } else if (use_xt) {
        const int j  = blockIdx.x - 1024;        // 0..6911
        const int bg = wv;                       // b-group of 16
        if (lane < 32) {
            const int bl = lane & 15, kq = lane >> 4;
            const float* xp = x + ((size_t)(bg * 16 + bl) * IC + j) * 16 + kq * 8;
            float4 x0 = *(const float4*)xp;
            float4 x1 = *(const float4*)(xp + 4);
            bf16x8 fr;
            fr[0] = (short)f2bf(x0.x); fr[1] = (short)f2bf(x0.y);
            fr[2] = (short)f2bf(x0.z); fr[3] = (short)f2bf(x0.w);
            fr[4] = (short)f2bf(x1.x); fr[5] = (short)f2bf(x1.y);
            fr[6] = (short)f2bf(x1.z); fr[7] = (short)f2bf(x1.w);
            *(bf16x8*)&x_t[((size_t)j * 4 + bg) * 256 + lane * 8] = fr;
        }
    }
}

// Routing sweep, two-pass MFMA + explicit double buffer, vv in LDS.
// Block 256 = 4 waves = bg_l(2) x jw(2); covers 32 b's (bh half), 18 j's.
// Layouts (R2/R5-proven): A[m=o=lane&15][k=(lane>>4)*8+t], B[k][b=lane&15],
// D col=lane&15(=b) row=(lane>>4)*4+reg(=o); K 16->32 zero-padded via zero
// fragments on lanes>=32 (outputs on ALL lanes are valid).
__global__ __launch_bounds__(256, 3) void sweep_kernel(
    const float* __restrict__ x, const unsigned short* __restrict__ x_t,
    const unsigned short* __restrict__ w_t, const float* __restrict__ vsum,
    float* __restrict__ part, int iter, int use_xt)
{
    __shared__ float smem[32 * 164];      // vv tile during loop; cbuf at end

    const int tid  = threadIdx.x;
    const int lane = tid & 63;
    const int wave = tid >> 6;
    const int bl   = lane & 15;
    const int kq   = lane >> 4;
    const bool act = (lane < 32);
    const int bh   = blockIdx.x & 1;
    const int jg   = blockIdx.x >> 1;
    const int bg_l = wave & 1;
    const int jw   = wave >> 1;
    const int b    = bh * 32 + bg_l * 16 + bl;
    const int j0   = jg * 18 + jw * 9;
    const int vrow = (bg_l * 16 + bl) * 164;

    const f32x4 zf = (f32x4){0.f, 0.f, 0.f, 0.f};
    const bf16x8 zb = (bf16x8){0, 0, 0, 0, 0, 0, 0, 0};

    if (iter > 0) {
        for (int idx = tid; idx < 5120; idx += 256)
            smem[(idx / 160) * 164 + (idx % 160)] = vsum[bh * 5120 + idx];
    }
    __syncthreads();

    f32x4 sac[NCAP];
    #pragma unroll
    for (int n = 0; n < NCAP; ++n) sac[n] = zf;

    // ---- load fragments for j0 ----
    bf16x8 fw[NCAP]; bf16x8 fx;
    fx = zb;
    #pragma unroll
    for (int n = 0; n < NCAP; ++n) fw[n] = zb;
    if (act) {
        if (use_xt) {
            fx = *(const bf16x8*)&x_t[((size_t)j0 * 4 + bh * 2 + bg_l) * 256 + lane * 8];
        } else {
            const float* xp = x + ((size_t)b * IC + j0) * 16 + kq * 8;
            float4 x0 = *(const float4*)xp, x1 = *(const float4*)(xp + 4);
            fx[0] = (short)f2bf(x0.x); fx[1] = (short)f2bf(x0.y);
            fx[2] = (short)f2bf(x0.z); fx[3] = (short)f2bf(x0.w);
            fx[4] = (short)f2bf(x1.x); fx[5] = (short)f2bf(x1.y);
            fx[6] = (short)f2bf(x1.z); fx[7] = (short)f2bf(x1.w);
        }
        #pragma unroll
        for (int n = 0; n < NCAP; ++n)
            fw[n] = *(const bf16x8*)&w_t[((size_t)j0 * NCAP + n) * 256 + lane * 8];
    }

    #pragma unroll
    for (int jt = 0; jt < 9; ++jt) {
        // ---- prefetch j+1 ----
        bf16x8 nw_[NCAP]; bf16x8 nx;
        nx = zb;
        #pragma unroll
        for (int n = 0; n < NCAP; ++n) nw_[n] = zb;
        if (jt < 8) {
            const int j1 = j0 + jt + 1;
            if (act) {
                if (use_xt) {
                    nx = *(const bf16x8*)&x_t[((size_t)j1 * 4 + bh * 2 + bg_l) * 256 + lane * 8];
                } else {
                    const float* xp = x + ((size_t)b * IC + j1) * 16 + kq * 8;
                    float4 x0 = *(const float4*)xp, x1 = *(const float4*)(xp + 4);
                    nx[0] = (short)f2bf(x0.x); nx[1] = (short)f2bf(x0.y);
                    nx[2] = (short)f2bf(x0.z); nx[3] = (short)f2bf(x0.w);
                    nx[4] = (short)f2bf(x1.x); nx[5] = (short)f2bf(x1.y);
                    nx[6] = (short)f2bf(x1.z); nx[7] = (short)f2bf(x1.w);
                }
                #pragma unroll
                for (int n = 0; n < NCAP; ++n)
                    nw_[n] = *(const bf16x8*)&w_t[((size_t)j1 * NCAP + n) * 256 + lane * 8];
            }
        }

        // ---- compute on current j ----
        if (iter == 0) {
            #pragma unroll
            for (int n = 0; n < NCAP; ++n) {
                f32x4 u4 = __builtin_amdgcn_mfma_f32_16x16x32_bf16(fw[n], fx, zf, 0, 0, 0);
                sac[n][0] = fmaf(0.1f, u4[0], sac[n][0]);
                sac[n][1] = fmaf(0.1f, u4[1], sac[n][1]);
                sac[n][2] = fmaf(0.1f, u4[2], sac[n][2]);
                sac[n][3] = fmaf(0.1f, u4[3], sac[n][3]);
            }
        } else {
            // pass 1: routing logits (u transient)
            float bb_[NCAP];
            #pragma unroll
            for (int n = 0; n < NCAP; ++n) {
                f32x4 u4 = __builtin_amdgcn_mfma_f32_16x16x32_bf16(fw[n], fx, zf, 0, 0, 0);
                f32x4 vvn = *(const f32x4*)&smem[vrow + n * 16 + kq * 4];
                float p = u4[0] * vvn[0] + u4[1] * vvn[1]
                        + u4[2] * vvn[2] + u4[3] * vvn[3];
                p += __shfl_xor(p, 16);
                p += __shfl_xor(p, 32);
                bb_[n] = p;
            }
            float ssum = 0.f;
            float c[NCAP];
            #pragma unroll
            for (int n = 0; n < NCAP; ++n) { c[n] = __expf(bb_[n]); ssum += c[n]; }
            const float inv = 1.0f / ssum;
            // pass 2: re-MFMA and accumulate
            #pragma unroll
            for (int n = 0; n < NCAP; ++n) {
                f32x4 u4 = __builtin_amdgcn_mfma_f32_16x16x32_bf16(fw[n], fx, zf, 0, 0, 0);
                const float cn = c[n] * inv;
                sac[n][0] = fmaf(cn, u4[0], sac[n][0]);
                sac[n][1] = fmaf(cn, u4[1], sac[n][1]);
                sac[n][2] = fmaf(cn, u4[2], sac[n][2]);
                sac[n][3] = fmaf(cn, u4[3], sac[n][3]);
            }
        }

        // rotate buffers (vanishes under full unroll)
        fx = nx;
        #pragma unroll
        for (int n = 0; n < NCAP; ++n) fw[n] = nw_[n];
    }

    // ---- combine jw=1 into jw=0 and store partial ----
    __syncthreads();                       // everyone done reading vv region
    const int sb = (bg_l * 16 + bl) * 164 + kq * 4;
    if (jw == 1) {
        #pragma unroll
        for (int n = 0; n < NCAP; ++n)
            *(f32x4*)&smem[sb + n * 16] = sac[n];
    }
    __syncthreads();
    if (jw == 0) {
        float* pp = part + (size_t)blockIdx.x * 5120;
        #pragma unroll
        for (int n = 0; n < NCAP; ++n) {
            f32x4 t = *(const f32x4*)&smem[sb + n * 16];
            t[0] += sac[n][0]; t[1] += sac[n][1];
            t[2] += sac[n][2]; t[3] += sac[n][3];
            *(f32x4*)&pp[(bg_l * 16 + bl) * 160 + n * 16 + kq * 4] = t;
        }
    }
}

// Fused reduce (NSLOT slots -> s) + squash + vsum/out. Grid 160 x 256.
__global__ __launch_bounds__(256) void reduce_kernel(
    const float* __restrict__ part, float* __restrict__ vsum,
    float* __restrict__ out, int iter)
{
    __shared__ float lds[3 * 64];
    const int tid = threadIdx.x;
    const int gi = tid & 63, rq = tid >> 6;
    const int g  = blockIdx.x * 64 + gi;          // 0..10239
    const int bh = (g >= 5120) ? 1 : 0;
    const float* p0 = part + bh * 5120 + (g - bh * 5120);
    float acc = 0.f;
    for (int k = rq * 96; k < rq * 96 + 96; ++k)
        acc += p0[(size_t)k * 10240];
    if (rq > 0) lds[(rq - 1) * 64 + gi] = acc;
    __syncthreads();
    if (rq == 0) {
        acc += lds[gi] + lds[64 + gi] + lds[128 + gi];
        float sq = acc * acc;                     // squash over o = bits 0..3
        sq += __shfl_xor(sq, 1);
        sq += __shfl_xor(sq, 2);
        sq += __shfl_xor(sq, 4);
        sq += __shfl_xor(sq, 8);
        float scale = (sq / (1.f + sq)) / sqrtf(sq + 1e-7f);
        float v = scale * acc;
        if (iter == 2)      out[g] = v;
        else if (iter == 0) vsum[g] = v;
        else                vsum[g] += v;
    }
}

extern "C" void kernel_launch(void* const* d_in, const int* in_sizes, int n_in,
                              void* d_out, int out_size, void* d_ws, size_t ws_size,
                              hipStream_t stream) {
    (void)in_sizes; (void)n_in; (void)out_size;
    const float* x = (const float*)d_in[0];   // [64, 6912, 16]
    const float* W = (const float*)d_in[1];   // [10, 6912, 16, 16]
    float* out = (float*)d_out;               // [64, 10, 16]

    const size_t wt_sh = (size_t)IC * NCAP * 256;   // shorts (35.4 MB)
    const size_t xt_sh = (size_t)IC * 4 * 256;      // shorts (14.2 MB)
    const size_t part_f = (size_t)NSLOT * 5120;     // floats (15.7 MB)
    const size_t need_xt = wt_sh * 2 + xt_sh * 2 + part_f * 4 + 10240 * 4;

    int use_xt = (ws_size >= need_xt) ? 1 : 0;
    unsigned short* w_t = (unsigned short*)d_ws;
    unsigned short* x_t = use_xt ? (w_t + wt_sh) : nullptr;
    float* part = (float*)(use_xt ? (void*)(x_t + xt_sh) : (void*)(w_t + wt_sh));
    float* vsum = part + part_f;

    prep_kernel<<<use_xt ? (1024 + IC) : 1024, 256, 0, stream>>>(x, W, w_t, x_t, use_xt);
    for (int iter = 0; iter < 3; ++iter) {
        sweep_kernel<<<NSLOT, 256, 0, stream>>>(x, x_t, w_t, vsum, part, iter, use_xt);
        reduce_kernel<<<160, 256, 0, stream>>>(part, vsum, out, iter);
    }
}